// Round 9
// baseline (144.642 us; speedup 1.0000x reference)
//
#include <hip/hip_runtime.h>
#include <math.h>

#define BB 4
#define LL 512
#define EMB 256
#define NH 8
#define HD 32
#define NB_ 3
#define CCN 10
#define NBKT 32
#define SCALE 0.17677669529663687f

typedef __bf16 bf16_t;
typedef __attribute__((ext_vector_type(8))) bf16_t bf16x8;
typedef __attribute__((ext_vector_type(4))) float f32x4;

__device__ __forceinline__ unsigned short f2b(float f) {
    unsigned int u = __float_as_uint(f);
    u += 0x7FFF + ((u >> 16) & 1);   // RNE
    return (unsigned short)(u >> 16);
}
__device__ __forceinline__ float b2f(unsigned short s) {
    return __uint_as_float(((unsigned int)s) << 16);
}
__device__ __forceinline__ unsigned pack2(float a, float b) {
    return (unsigned)f2b(a) | ((unsigned)f2b(b) << 16);
}
__device__ __forceinline__ int bm_of(int tq, int tk) {
    return (tq * tk != 0) ? ((tq - 1) * 3 + tk) : 0;
}
__device__ __forceinline__ unsigned long long shfl_up64(unsigned long long v, int d) {
    unsigned lo = (unsigned)__shfl_up((int)(unsigned)v, d, 64);
    unsigned hi = (unsigned)__shfl_up((int)(v >> 32), d, 64);
    return (((unsigned long long)hi) << 32) | lo;
}

// Stable counting sort of 512 tokens by type (4 types), 256 threads.
__device__ __forceinline__ void sort512(const int* __restrict__ tsb, int* spk,
                                        unsigned long long* wtll, int* msc, int tid) {
    int ty0 = tsb[2 * tid], ty1 = tsb[2 * tid + 1];
    unsigned long long pk = (1ULL << (16 * ty0)) + (1ULL << (16 * ty1));
    unsigned long long v = pk;
    int lane = tid & 63;
#pragma unroll
    for (int off = 1; off < 64; off <<= 1) {
        unsigned long long o = shfl_up64(v, off);
        if (lane >= off) v += o;
    }
    int w = tid >> 6;
    if (lane == 63) wtll[w] = v;
    __syncthreads();
    unsigned long long pre = 0, tot = 0;
#pragma unroll
    for (int i = 0; i < 4; i++) {
        unsigned long long xx = wtll[i];
        if (i < w) pre += xx;
        tot += xx;
    }
    v += pre;
    unsigned long long excl = v - pk;
    int c0 = (int)(tot & 0xFFFF), c1 = (int)((tot >> 16) & 0xFFFF);
    int c2 = (int)((tot >> 32) & 0xFFFF), c3 = (int)((tot >> 48) & 0xFFFF);
    int ub0 = 0, ub1 = c0, ub2 = c0 + c1, ub3 = c0 + c1 + c2;
    if (tid == 0) {
        int pc0 = (c0 + 31) & ~31, pc1 = (c1 + 31) & ~31, pc2 = (c2 + 31) & ~31, pc3 = (c3 + 31) & ~31;
        int pb1 = pc0, pb2 = pc0 + pc1, pb3 = pc0 + pc1 + pc2;
        msc[0] = 0;  msc[1] = pb1; msc[2] = pb2; msc[3] = pb3;
        msc[4] = ub0; msc[5] = ub1; msc[6] = ub2; msc[7] = ub3;
        msc[8] = c0; msc[9] = c1; msc[10] = c2; msc[11] = c3;
        msc[12] = (pb3 + pc3 + 63) & ~63;
    }
    int bases[4] = {ub0, ub1, ub2, ub3};
    int r0 = (int)((excl >> (16 * ty0)) & 0xFFFF);
    unsigned long long excl1 = excl + (1ULL << (16 * ty0));
    int r1 = (int)((excl1 >> (16 * ty1)) & 0xFFFF);
    spk[bases[ty0] + r0] = (ty0 << 16) | (2 * tid);
    spk[bases[ty1] + r1] = (ty1 << 16) | (2 * tid + 1);
    __syncthreads();
}

__device__ __forceinline__ void pad_lookup(const int* msc, int pos, int& real, int& upos, int& seg) {
    seg = (pos >= msc[1]) + (pos >= msc[2]) + (pos >= msc[3]);
    int r = pos - msc[seg];
    real = (r < msc[8 + seg]) ? 1 : 0;
    upos = msc[4 + seg] + r;
}

// ---------------- K0: weight combine + QKV weight transpose + mask-zero check ----------------
__global__ void k_pre(const float* __restrict__ A1, const float* __restrict__ W1,
                      const float* __restrict__ A2, const float* __restrict__ W2,
                      const float* __restrict__ Wq, const float* __restrict__ Wk, const float* __restrict__ Wv,
                      const float* __restrict__ am,
                      float* __restrict__ W1s, float* __restrict__ W2s,
                      unsigned short* __restrict__ W1Tb, unsigned short* __restrict__ W2Tb,
                      unsigned short* __restrict__ Wt, int* __restrict__ mflag) {
    __shared__ float cmb[32 * 33];
    __shared__ unsigned short ls[64 * 264];
    int g = blockIdx.x, tid = threadIdx.x;
    if (g < 160) {
        int idx = g;
        const float* alpha = (idx < 80) ? A1 : A2;
        const float* W     = (idx < 80) ? W1 : W2;
        float* Ws          = (idx < 80) ? W1s : W2s;
        unsigned short* WT = (idx < 80) ? W1Tb : W2Tb;
        idx %= 80;
        int cc = idx / NH, h = idx % NH;
        float a0 = alpha[cc * NB_ * NH + 0 * NH + h];
        float a1 = alpha[cc * NB_ * NH + 1 * NH + h];
        float a2 = alpha[cc * NB_ * NH + 2 * NH + h];
        float mx = fmaxf(a0, fmaxf(a1, a2));
        float e0 = __expf(a0 - mx), e1 = __expf(a1 - mx), e2 = __expf(a2 - mx);
        float inv = 1.0f / (e0 + e1 + e2);
        e0 *= inv; e1 *= inv; e2 *= inv;
        for (int i = tid; i < HD * HD; i += 256) {
            int m = i >> 5, n = i & 31;
            float acc = e0 * W[((0 * NH + h) * HD + m) * HD + n]
                      + e1 * W[((1 * NH + h) * HD + m) * HD + n]
                      + e2 * W[((2 * NH + h) * HD + m) * HD + n];
            cmb[m * 33 + n] = acc;
        }
        __syncthreads();
        for (int i = tid; i < HD * HD; i += 256) {
            int a = i >> 5, bq = i & 31;
            Ws[((cc * NH + h) * HD + a) * HD + bq] = cmb[a * 33 + bq];
            WT[((size_t)(cc * NH + h) * HD + a) * HD + bq] = f2b(cmb[bq * 33 + a]);
        }
        return;
    }
    if (g < 208) {  // transpose Wq/Wk/Wv
        int t = g - 160;
        int tw = t >> 2, ob = t & 3;
        int which = tw >> 2, ty = tw & 3;
        const float* src = ((which == 0) ? Wq : (which == 1) ? Wk : Wv) + (size_t)ty * EMB * EMB;
        int out0 = ob * 64;
        for (int it = 0; it < 16; it++) {
            int e = it * 16 + (tid >> 4);
            int o4 = (tid & 15) * 4;
            float4 v = *(const float4*)&src[(size_t)e * EMB + out0 + o4];
            ls[(o4 + 0) * 264 + e] = f2b(v.x);
            ls[(o4 + 1) * 264 + e] = f2b(v.y);
            ls[(o4 + 2) * 264 + e] = f2b(v.z);
            ls[(o4 + 3) * 264 + e] = f2b(v.w);
        }
        __syncthreads();
        int out = tid >> 2, ech = (tid & 3) * 8;
        unsigned short* dst = Wt + (size_t)tw * EMB * EMB + (size_t)(out0 + out) * EMB;
        const unsigned short* srcl = &ls[out * 264];
#pragma unroll
        for (int jj = 0; jj < 8; jj++)
            *(uint4*)&dst[ech + jj * 32] = *(const uint4*)&srcl[ech + jj * 32];
        return;
    }
    // mask-zero check: 256 blocks x 4096 floats
    {
        int idx = g - 208;
        const uint4* p = (const uint4*)am + (size_t)idx * 1024;
        unsigned o = 0;
#pragma unroll
        for (int j = 0; j < 4; j++) {
            uint4 v = p[tid + j * 256];
            o |= v.x | v.y | v.z | v.w;
        }
        if (o) atomicOr(mflag, 1);
    }
}

// ---------------- K1: QKV projection, direct-to-register MFMA (no GEMM-loop barriers) ----------------
__global__ __launch_bounds__(256, 4) void k_qkv(
    const float* __restrict__ x, const int* __restrict__ ts,
    const unsigned short* __restrict__ Wt,
    unsigned short* __restrict__ qp, unsigned short* __restrict__ kp, unsigned short* __restrict__ vp) {
    __shared__ int spk[LL];
    __shared__ unsigned long long wtll[4];
    __shared__ int msc[16];

    int g = blockIdx.x, tid = threadIdx.x;
    int ns = g % 6, gb = g / 6;
    int b = gb >> 4, tb = gb & 15, i0 = tb * 32;
    int which = ns >> 1, nh = ns & 1;
    int wave = tid >> 6, lane = tid & 63, quad = lane >> 4, col = lane & 15;

    sort512(ts + b * LL, spk, wtll, msc, tid);

    // preload A-frags (x rows, sorted) straight into registers
    bf16x8 afr[2][8];
#pragma unroll
    for (int mt = 0; mt < 2; mt++) {
        int orig = spk[i0 + mt * 16 + col] & 0xFFFF;
        const float* xr = &x[(size_t)(b * LL + orig) * EMB];
#pragma unroll
        for (int kc = 0; kc < 8; kc++) {
            float4 v0 = *(const float4*)&xr[kc * 32 + quad * 8];
            float4 v1 = *(const float4*)&xr[kc * 32 + quad * 8 + 4];
            uint4 up;
            up.x = pack2(v0.x, v0.y); up.y = pack2(v0.z, v0.w);
            up.z = pack2(v1.x, v1.y); up.w = pack2(v1.z, v1.w);
            afr[mt][kc] = *(bf16x8*)&up;
        }
    }
    int t_start = spk[i0] >> 16, t_end = spk[i0 + 31] >> 16;
    unsigned short* outp = (which == 0) ? qp : (which == 1) ? kp : vp;

    for (int ty = t_start; ty <= t_end; ty++) {
        f32x4 acc[2][2];
#pragma unroll
        for (int mt = 0; mt < 2; mt++)
#pragma unroll
            for (int nt = 0; nt < 2; nt++) acc[mt][nt] = (f32x4){0.f, 0.f, 0.f, 0.f};
        const unsigned short* wsrc = Wt + (size_t)(which * 4 + ty) * EMB * EMB + (size_t)(nh * 128) * EMB;
        const unsigned short* w0 = &wsrc[(size_t)((wave * 2 + 0) * 16 + col) * EMB + quad * 8];
        const unsigned short* w1 = &wsrc[(size_t)((wave * 2 + 1) * 16 + col) * EMB + quad * 8];
#pragma unroll
        for (int kc = 0; kc < 8; kc++) {
            bf16x8 b0 = *(const bf16x8*)&w0[kc * 32];
            bf16x8 b1 = *(const bf16x8*)&w1[kc * 32];
            acc[0][0] = __builtin_amdgcn_mfma_f32_16x16x32_bf16(afr[0][kc], b0, acc[0][0], 0, 0, 0);
            acc[0][1] = __builtin_amdgcn_mfma_f32_16x16x32_bf16(afr[0][kc], b1, acc[0][1], 0, 0, 0);
            acc[1][0] = __builtin_amdgcn_mfma_f32_16x16x32_bf16(afr[1][kc], b0, acc[1][0], 0, 0, 0);
            acc[1][1] = __builtin_amdgcn_mfma_f32_16x16x32_bf16(afr[1][kc], b1, acc[1][1], 0, 0, 0);
        }
#pragma unroll
        for (int mt = 0; mt < 2; mt++)
#pragma unroll
            for (int r = 0; r < 4; r++) {
                int tokloc = mt * 16 + quad * 4 + r;
                int tty = spk[i0 + tokloc] >> 16;
                if (tty != ty) continue;
#pragma unroll
                for (int nt = 0; nt < 2; nt++) {
                    int n = nh * 128 + (wave * 2 + nt) * 16 + col;
                    int h = n >> 5, d = n & 31;
                    outp[((size_t)(b * NH + h) * LL + i0 + tokloc) * HD + d] = f2b(acc[mt][nt][r]);
                }
            }
    }
}

// ---------------- K2: attention core ----------------
#define SCP 648
#define OFF_UN   20736
#define OFF_QTB  29184
#define OFF_KPAD 33536
#define OFF_TBL  36096
#define OFF_RPL  37120
#define OFF_WT   38400
#define OFF_QOR  38432
#define OFF_QTY  38496
#define OFF_INV  38560
#define OFF_MSC  38624
#define SM_TOTAL 38688
__global__ __launch_bounds__(256, 4) void k_attn(
    const unsigned short* __restrict__ qp, const unsigned short* __restrict__ kp,
    const unsigned short* __restrict__ vp,
    const int* __restrict__ ts, const float* __restrict__ rp, const float* __restrict__ am,
    const float* __restrict__ W1s, const float* __restrict__ W2s,
    const unsigned short* __restrict__ W1Tb, const unsigned short* __restrict__ W2Tb,
    const int* __restrict__ mflag, float* __restrict__ ctx) {
    __shared__ __align__(16) char smem[SM_TOTAL];
    unsigned short* scu = (unsigned short*)smem;
    int*   spk  = (int*)smem;
    unsigned short* qstb = (unsigned short*)(smem + OFF_UN);   // [16*40]
    unsigned short* vt   = (unsigned short*)(smem + OFF_UN);   // [32*72]
    float* sb   = (float*)(smem + OFF_UN);                     // [16*132]
    unsigned short* qtb = (unsigned short*)(smem + OFF_QTB);   // [16*136] / later sbb
    unsigned short* sbb = (unsigned short*)(smem + OFF_QTB);
    int*   kpad = (int*)(smem + OFF_KPAD);                     // [640]: ty<<20 | upos<<10 | orig (orig=0x3FF pad)
    short* tbl  = (short*)(smem + OFF_TBL);
    float* rp_l = (float*)(smem + OFF_RPL);
    unsigned long long* wtll = (unsigned long long*)(smem + OFF_WT);
    int*   qor_l = (int*)(smem + OFF_QOR);
    int*   qty_l = (int*)(smem + OFF_QTY);
    float* inv_l = (float*)(smem + OFF_INV);
    int*   msc   = (int*)(smem + OFF_MSC);

    int blk = blockIdx.x;
    int b = blk >> 8, h = (blk >> 5) & 7, q16 = blk & 31;
    int i0q = q16 * 16;
    int tid = threadIdx.x;
    int wave = tid >> 6, lane = tid & 63, quad = lane >> 4, col = lane & 15;
    int bh = b * NH + h;
    int mz = (mflag[0] == 0);

    for (int d = tid; d < LL; d += 256) {
        int v;
        if (d < 8) v = d;
        else {
            double r = log((double)d / 8.0) / log(5.0);
            v = 8 + (int)(r * 8.0);
            if (v > 15) v = 15;
        }
        tbl[d] = (short)v;
    }
    for (int i = tid; i < CCN * NBKT; i += 256) rp_l[i] = rp[i * NH + h];

    sort512(ts + b * LL, spk, wtll, msc, tid);

    int KT = msc[12];
    if (tid < 16) {
        int v = spk[i0q + tid];
        qor_l[tid] = v & 0xFFFF; qty_l[tid] = v >> 16;
    }
    for (int pos = tid; pos < KT; pos += 256) {
        int real, upos, seg;
        pad_lookup(msc, pos, real, upos, seg);
        int orig = real ? (spk[upos] & 0xFFFF) : 0x3FF;
        kpad[pos] = (seg << 20) | ((real ? upos : 0) << 10) | orig;
    }
    {   // stage 16 q rows (bf16, pitch 40)
        int q = tid >> 4, m2 = (tid & 15) * 2;
        ((unsigned*)qstb)[q * 20 + (tid & 15)] =
            *(const unsigned*)&qp[((size_t)bh * LL + i0q + q) * HD + m2];
    }
    __syncthreads();

    int qor_r[4], qty_r[4];
#pragma unroll
    for (int r = 0; r < 4; r++) { qor_r[r] = qor_l[quad * 4 + r]; qty_r[r] = qty_l[quad * 4 + r]; }
    bool uniq = (qty_l[0] == qty_l[15]);
    int tqu = qty_l[0];

    // ---- qt ----
    if (uniq) {
#pragma unroll
        for (int it = 0; it < 2; it++) {
            int t8 = wave * 2 + it;
            int tk = t8 >> 1, nhf = t8 & 1;
            int bmv = bm_of(tqu, tk);
            bf16x8 a = *(const bf16x8*)&qstb[col * 40 + quad * 8];
            bf16x8 bb = *(const bf16x8*)&W1Tb[((size_t)(bmv * NH + h) * HD + nhf * 16 + col) * HD + quad * 8];
            f32x4 d = {0.f, 0.f, 0.f, 0.f};
            d = __builtin_amdgcn_mfma_f32_16x16x32_bf16(a, bb, d, 0, 0, 0);
#pragma unroll
            for (int r = 0; r < 4; r++)
                qtb[(quad * 4 + r) * 136 + tk * 32 + nhf * 16 + col] = f2b(d[r]);
        }
    } else {
        for (int i = tid; i < 16 * 128; i += 256) {
            int q = i >> 7, r = i & 127, tk = r >> 5, n = r & 31;
            int bmv = bm_of(qty_l[q], tk);
            const float* wb = &W1s[((bmv * NH + h) * HD) * HD + n];
            float acc = 0.f;
#pragma unroll
            for (int m = 0; m < HD; m++) acc += b2f(qstb[q * 40 + m]) * wb[m * HD];
            qtb[q * 136 + tk * 32 + n] = f2b(acc);
        }
    }
    __syncthreads();

    // ---- pass 1: scores, barrier-free, direct K loads ----
    const float* amb = am + (size_t)b * LL * LL;
    int ntiles = KT >> 4;
    for (int tile = wave; tile < ntiles; tile += 4) {
        int kb = tile * 16;
        int kv0 = kpad[kb];
        if ((kv0 & 0x3FF) == 0x3FF) {   // all-pad tile
#pragma unroll
            for (int r = 0; r < 4; r++) scu[(quad * 4 + r) * SCP + kb + col] = 0xFF80;
            continue;
        }
        int tkt = kv0 >> 20;
        int kpi = kb + col;
        int kv = kpad[kpi];
        int ko = kv & 0x3FF;
        int upos = (kv >> 10) & 0x3FF;
        bool real = (ko != 0x3FF);
        bf16x8 bfr;
        if (real) bfr = *(const bf16x8*)&kp[((size_t)bh * LL + upos) * HD + quad * 8];
        else { uint4 z = make_uint4(0, 0, 0, 0); bfr = *(bf16x8*)&z; }
        bf16x8 a = *(const bf16x8*)&qtb[col * 136 + tkt * 32 + quad * 8];
        f32x4 d = {0.f, 0.f, 0.f, 0.f};
        d = __builtin_amdgcn_mfma_f32_16x16x32_bf16(a, bfr, d, 0, 0, 0);
        if (!real) {
#pragma unroll
            for (int r = 0; r < 4; r++) scu[(quad * 4 + r) * SCP + kpi] = 0xFF80;
        } else {
#pragma unroll
            for (int r = 0; r < 4; r++) {
                int q = quad * 4 + r;
                int qo = qor_r[r];
                int dd = qo - ko;
                int ad = dd < 0 ? -dd : dd;
                int bk = (dd < 0 ? 16 : 0) + (int)tbl[ad];
                float sv = d[r] * SCALE + rp_l[bm_of(qty_r[r], tkt) * NBKT + bk];
                if (!mz) sv += amb[(size_t)qo * LL + ko];
                scu[q * SCP + kpi] = f2b(sv);
            }
        }
    }
    __syncthreads();

    // ---- pass 2: softmax ----
    {
        int gq = tid >> 4, t16 = tid & 15;
        float mx = -1e30f;
        for (int kk = t16; kk < KT; kk += 16) mx = fmaxf(mx, b2f(scu[gq * SCP + kk]));
#pragma unroll
        for (int off = 1; off < 16; off <<= 1) mx = fmaxf(mx, __shfl_xor(mx, off, 16));
        float sum = 0.f;
        for (int kk = t16; kk < KT; kk += 16) {
            int idx = gq * SCP + kk;
            float e = __expf(b2f(scu[idx]) - mx);
            scu[idx] = f2b(e); sum += e;
        }
#pragma unroll
        for (int off = 1; off < 16; off <<= 1) sum += __shfl_xor(sum, off, 16);
        if (t16 == 0) inv_l[gq] = 1.0f / sum;
    }
    __syncthreads();

    // ---- pass 3: PV via MFMA (vt rows permuted) ----
    f32x4 accv[4][2];
#pragma unroll
    for (int t = 0; t < 4; t++)
#pragma unroll
        for (int hh = 0; hh < 2; hh++) accv[t][hh] = (f32x4){0.f, 0.f, 0.f, 0.f};

    for (int kt0 = 0; kt0 < KT; kt0 += 64) {
        {
            int kk = tid >> 2, n8 = (tid & 3) * 8;
            int kv = kpad[kt0 + kk];
            int upos = (kv >> 10) & 0x3FF;
            bool real = ((kv & 0x3FF) != 0x3FF);
            uint4 w = make_uint4(0, 0, 0, 0);
            if (real) w = *(const uint4*)&vp[((size_t)bh * LL + upos) * HD + n8];
            unsigned short sv[8] = {
                (unsigned short)(w.x & 0xFFFF), (unsigned short)(w.x >> 16),
                (unsigned short)(w.y & 0xFFFF), (unsigned short)(w.y >> 16),
                (unsigned short)(w.z & 0xFFFF), (unsigned short)(w.z >> 16),
                (unsigned short)(w.w & 0xFFFF), (unsigned short)(w.w >> 16)};
#pragma unroll
            for (int i = 0; i < 8; i++) {
                int n = n8 + i;
                int ph = ((n & 3) << 3) | (n >> 2);
                vt[ph * 72 + kk] = sv[i];
            }
        }
        __syncthreads();
        int c = kt0 >> 6;
        int g0 = 2 * c;
        int pc = ((col & 3) << 3) | (col >> 2);
#pragma unroll
        for (int gl = 0; gl < 2; gl++) {
            int gg = g0 + gl;
            if ((gg & 3) != wave) continue;
            int loc = gl * 32;
            int kvg = kpad[kt0 + loc];
            if ((kvg & 0x3FF) == 0x3FF) continue;   // all-pad group
            int tk = kvg >> 20;
            bf16x8 a = *(const bf16x8*)&scu[col * SCP + kt0 + loc + quad * 8];
            bf16x8 b0 = *(const bf16x8*)&vt[pc * 72 + loc + quad * 8];
            bf16x8 b1 = *(const bf16x8*)&vt[(pc + 4) * 72 + loc + quad * 8];
            if (tk == 0) {
                accv[0][0] = __builtin_amdgcn_mfma_f32_16x16x32_bf16(a, b0, accv[0][0], 0, 0, 0);
                accv[0][1] = __builtin_amdgcn_mfma_f32_16x16x32_bf16(a, b1, accv[0][1], 0, 0, 0);
            } else if (tk == 1) {
                accv[1][0] = __builtin_amdgcn_mfma_f32_16x16x32_bf16(a, b0, accv[1][0], 0, 0, 0);
                accv[1][1] = __builtin_amdgcn_mfma_f32_16x16x32_bf16(a, b1, accv[1][1], 0, 0, 0);
            } else if (tk == 2) {
                accv[2][0] = __builtin_amdgcn_mfma_f32_16x16x32_bf16(a, b0, accv[2][0], 0, 0, 0);
                accv[2][1] = __builtin_amdgcn_mfma_f32_16x16x32_bf16(a, b1, accv[2][1], 0, 0, 0);
            } else {
                accv[3][0] = __builtin_amdgcn_mfma_f32_16x16x32_bf16(a, b0, accv[3][0], 0, 0, 0);
                accv[3][1] = __builtin_amdgcn_mfma_f32_16x16x32_bf16(a, b1, accv[3][1], 0, 0, 0);
            }
        }
        __syncthreads();
    }

    // ---- cross-wave reduction; last wave emits bf16 sbb ----
#pragma unroll
    for (int w = 0; w < 4; w++) {
        if (wave == w) {
#pragma unroll
            for (int t = 0; t < 4; t++)
#pragma unroll
                for (int hh = 0; hh < 2; hh++)
#pragma unroll
                    for (int r = 0; r < 4; r++) {
                        int q = quad * 4 + r;
                        int n = col + 16 * hh;
                        float val = accv[t][hh][r];
                        if (w == 0) {
                            sb[q * 132 + t * 32 + n] = val;
                        } else if (w < 3) {
                            sb[q * 132 + t * 32 + n] += val;
                        } else {
                            float fin = sb[q * 132 + t * 32 + n] + val;
                            sb[q * 132 + t * 32 + n] = fin;
                            sbb[q * 136 + t * 32 + n] = f2b(fin);
                        }
                    }
        }
        __syncthreads();
    }

    // ---- ctx epilogue ----
    if (uniq) {
        if (wave < 2) {
            int mhf = wave;
            f32x4 d = {0.f, 0.f, 0.f, 0.f};
#pragma unroll
            for (int tk = 0; tk < 4; tk++) {
                int bmv = bm_of(tqu, tk);
                bf16x8 a = *(const bf16x8*)&sbb[col * 136 + tk * 32 + quad * 8];
                bf16x8 bb = *(const bf16x8*)&W2Tb[((size_t)(bmv * NH + h) * HD + mhf * 16 + col) * HD + quad * 8];
                d = __builtin_amdgcn_mfma_f32_16x16x32_bf16(a, bb, d, 0, 0, 0);
            }
#pragma unroll
            for (int r = 0; r < 4; r++) {
                int q = quad * 4 + r;
                ctx[((size_t)(b * LL + qor_l[q])) * EMB + h * HD + mhf * 16 + col] = d[r] * inv_l[q];
            }
        }
    } else {
        int m = tid & 31, qq = tid >> 5;
#pragma unroll
        for (int rep = 0; rep < 2; rep++) {
            int qi = qq + 8 * rep;
            int tq = qty_l[qi];
            float acc = 0.f;
#pragma unroll
            for (int tk2 = 0; tk2 < 4; tk2++) {
                int bmv = bm_of(tq, tk2);
                const float* wb = &W2s[((bmv * NH + h) * HD) * HD + m];
                const float* sbp = &sb[qi * 132 + tk2 * 32];
                for (int n = 0; n < HD; n++) acc += sbp[n] * wb[n * HD];
            }
            int qo = qor_l[qi];
            ctx[((size_t)(b * LL + qo)) * EMB + h * HD + m] = acc * inv_l[qi];
        }
    }
}

// ---------------- K3: residual + LayerNorm ----------------
__global__ void k_ln(const float* __restrict__ ctx, const float* __restrict__ x,
                     const float* __restrict__ gamma, const float* __restrict__ beta,
                     float* __restrict__ out) {
    __shared__ float red[8];
    __shared__ float red2[8];
    int blk = blockIdx.x;
    int b = blk >> 9, l = blk & 511;
    int j = threadIdx.x;
    size_t base = ((size_t)(b * LL + l)) * EMB;
    float v = ctx[base + j] + x[base + j];
    float s = v, s2 = v * v;
    for (int off = 32; off > 0; off >>= 1) { s += __shfl_down(s, off, 64); s2 += __shfl_down(s2, off, 64); }
    int wid = j >> 6;
    if ((j & 63) == 0) { red[wid] = s; red2[wid] = s2; }
    __syncthreads();
    if (j == 0) {
        float ts_ = 0, ts2 = 0;
        for (int w = 0; w < 4; w++) { ts_ += red[w]; ts2 += red2[w]; }
        red[4] = ts_; red2[4] = ts2;
    }
    __syncthreads();
    float mu = red[4] / (float)EMB;
    float var = red2[4] / (float)EMB - mu * mu;
    float r = rsqrtf(var + 1e-12f);
    out[base + j] = (v - mu) * r * gamma[j] + beta[j];
}

extern "C" void kernel_launch(void* const* d_in, const int* in_sizes, int n_in,
                              void* d_out, int out_size, void* d_ws, size_t ws_size,
                              hipStream_t stream) {
    const float* x  = (const float*)d_in[0];
    const float* am = (const float*)d_in[1];
    const int*   ts = (const int*)d_in[2];
    const float* Wq = (const float*)d_in[3];
    const float* Wk = (const float*)d_in[4];
    const float* Wv = (const float*)d_in[5];
    const float* W1 = (const float*)d_in[6];
    const float* a1 = (const float*)d_in[7];
    const float* W2 = (const float*)d_in[8];
    const float* a2 = (const float*)d_in[9];
    const float* rp = (const float*)d_in[10];
    const float* g  = (const float*)d_in[11];
    const float* be = (const float*)d_in[12];
    float* out = (float*)d_out;

    float* ws  = (float*)d_ws;
    float* W1s = ws;                                        // 81920 f
    float* W2s = ws + 81920;                                // 81920 f
    unsigned short* W1Tb = (unsigned short*)(ws + 163840);  // 40960 f
    unsigned short* W2Tb = (unsigned short*)(ws + 204800);  // 40960 f
    int* mflag = (int*)(ws + 245760);                       // 16 f slot
    unsigned short* qp = (unsigned short*)(ws + 245776);    // 262144 f each (bf16)
    unsigned short* kp = qp + BB * NH * LL * HD;
    unsigned short* vp = kp + BB * NH * LL * HD;
    float* ctx = (float*)(vp + BB * NH * LL * HD);          // 524288 f
    unsigned short* Wt = (unsigned short*)ctx;              // aliases ctx (dead until k_attn)

    hipMemsetAsync(mflag, 0, 4, stream);
    hipLaunchKernelGGL(k_pre, dim3(464), dim3(256), 0, stream,
                       a1, W1, a2, W2, Wq, Wk, Wv, am, W1s, W2s, W1Tb, W2Tb, Wt, mflag);
    hipLaunchKernelGGL(k_qkv, dim3(384), dim3(256), 0, stream, x, ts, Wt, qp, kp, vp);
    hipLaunchKernelGGL(k_attn, dim3(BB * NH * 32), dim3(256), 0, stream,
                       qp, kp, vp, ts, rp, am, W1s, W2s, W1Tb, W2Tb, mflag, ctx);
    hipLaunchKernelGGL(k_ln, dim3(BB * LL), dim3(256), 0, stream, ctx, x, g, be, out);
}

// Round 10
// 140.672 us; speedup vs baseline: 1.0282x; 1.0282x over previous
//
#include <hip/hip_runtime.h>
#include <math.h>

#define BB 4
#define LL 512
#define EMB 256
#define NH 8
#define HD 32
#define NB_ 3
#define CCN 10
#define NBKT 32
#define SCALE 0.17677669529663687f

typedef __bf16 bf16_t;
typedef __attribute__((ext_vector_type(8))) bf16_t bf16x8;
typedef __attribute__((ext_vector_type(4))) float f32x4;

__device__ __forceinline__ unsigned short f2b(float f) {
    unsigned int u = __float_as_uint(f);
    u += 0x7FFF + ((u >> 16) & 1);   // RNE
    return (unsigned short)(u >> 16);
}
__device__ __forceinline__ float b2f(unsigned short s) {
    return __uint_as_float(((unsigned int)s) << 16);
}
__device__ __forceinline__ unsigned pack2(float a, float b) {
    return (unsigned)f2b(a) | ((unsigned)f2b(b) << 16);
}
__device__ __forceinline__ int bm_of(int tq, int tk) {
    return (tq * tk != 0) ? ((tq - 1) * 3 + tk) : 0;
}
__device__ __forceinline__ unsigned long long shfl_up64(unsigned long long v, int d) {
    unsigned lo = (unsigned)__shfl_up((int)(unsigned)v, d, 64);
    unsigned hi = (unsigned)__shfl_up((int)(v >> 32), d, 64);
    return (((unsigned long long)hi) << 32) | lo;
}

// Stable counting sort of 512 tokens by type (4 types), 256 threads.
// spk[pos]=(ty<<16)|orig. msc: [0..3] padded bases, [4..7] unpadded bases,
// [8..11] counts, [12] KT (padded total, mult of 64).
__device__ __forceinline__ void sort512(const int* __restrict__ tsb, int* spk,
                                        unsigned long long* wtll, int* msc, int tid) {
    int ty0 = tsb[2 * tid], ty1 = tsb[2 * tid + 1];
    unsigned long long pk = (1ULL << (16 * ty0)) + (1ULL << (16 * ty1));
    unsigned long long v = pk;
    int lane = tid & 63;
#pragma unroll
    for (int off = 1; off < 64; off <<= 1) {
        unsigned long long o = shfl_up64(v, off);
        if (lane >= off) v += o;
    }
    int w = tid >> 6;
    if (lane == 63) wtll[w] = v;
    __syncthreads();
    unsigned long long pre = 0, tot = 0;
#pragma unroll
    for (int i = 0; i < 4; i++) {
        unsigned long long xx = wtll[i];
        if (i < w) pre += xx;
        tot += xx;
    }
    v += pre;
    unsigned long long excl = v - pk;
    int c0 = (int)(tot & 0xFFFF), c1 = (int)((tot >> 16) & 0xFFFF);
    int c2 = (int)((tot >> 32) & 0xFFFF), c3 = (int)((tot >> 48) & 0xFFFF);
    int ub0 = 0, ub1 = c0, ub2 = c0 + c1, ub3 = c0 + c1 + c2;
    if (tid == 0) {
        int pc0 = (c0 + 31) & ~31, pc1 = (c1 + 31) & ~31, pc2 = (c2 + 31) & ~31, pc3 = (c3 + 31) & ~31;
        int pb1 = pc0, pb2 = pc0 + pc1, pb3 = pc0 + pc1 + pc2;
        msc[0] = 0;  msc[1] = pb1; msc[2] = pb2; msc[3] = pb3;
        msc[4] = ub0; msc[5] = ub1; msc[6] = ub2; msc[7] = ub3;
        msc[8] = c0; msc[9] = c1; msc[10] = c2; msc[11] = c3;
        msc[12] = (pb3 + pc3 + 63) & ~63;
    }
    int bases[4] = {ub0, ub1, ub2, ub3};
    int r0 = (int)((excl >> (16 * ty0)) & 0xFFFF);
    unsigned long long excl1 = excl + (1ULL << (16 * ty0));
    int r1 = (int)((excl1 >> (16 * ty1)) & 0xFFFF);
    spk[bases[ty0] + r0] = (ty0 << 16) | (2 * tid);
    spk[bases[ty1] + r1] = (ty1 << 16) | (2 * tid + 1);
    __syncthreads();
}

__device__ __forceinline__ void pad_lookup(const int* msc, int pos, int& real, int& upos, int& seg) {
    seg = (pos >= msc[1]) + (pos >= msc[2]) + (pos >= msc[3]);
    int r = pos - msc[seg];
    real = (r < msc[8 + seg]) ? 1 : 0;
    upos = msc[4 + seg] + r;
}

// ---------------- K0: weight combine + QKV weight transpose + per-block mask flags ----------------
__global__ void k_pre(const float* __restrict__ A1, const float* __restrict__ W1,
                      const float* __restrict__ A2, const float* __restrict__ W2,
                      const float* __restrict__ Wq, const float* __restrict__ Wk, const float* __restrict__ Wv,
                      const float* __restrict__ am,
                      float* __restrict__ W1s, float* __restrict__ W2s,
                      unsigned short* __restrict__ W1Tb, unsigned short* __restrict__ W2Tb,
                      unsigned short* __restrict__ Wt, int* __restrict__ mflagArr) {
    __shared__ float cmb[32 * 33];
    __shared__ unsigned short ls[64 * 264];
    __shared__ int reds[4];
    int g = blockIdx.x, tid = threadIdx.x;
    if (g < 160) {
        int idx = g;
        const float* alpha = (idx < 80) ? A1 : A2;
        const float* W     = (idx < 80) ? W1 : W2;
        float* Ws          = (idx < 80) ? W1s : W2s;
        unsigned short* WT = (idx < 80) ? W1Tb : W2Tb;
        idx %= 80;
        int cc = idx / NH, h = idx % NH;
        float a0 = alpha[cc * NB_ * NH + 0 * NH + h];
        float a1 = alpha[cc * NB_ * NH + 1 * NH + h];
        float a2 = alpha[cc * NB_ * NH + 2 * NH + h];
        float mx = fmaxf(a0, fmaxf(a1, a2));
        float e0 = __expf(a0 - mx), e1 = __expf(a1 - mx), e2 = __expf(a2 - mx);
        float inv = 1.0f / (e0 + e1 + e2);
        e0 *= inv; e1 *= inv; e2 *= inv;
        for (int i = tid; i < HD * HD; i += 256) {
            int m = i >> 5, n = i & 31;
            float acc = e0 * W[((0 * NH + h) * HD + m) * HD + n]
                      + e1 * W[((1 * NH + h) * HD + m) * HD + n]
                      + e2 * W[((2 * NH + h) * HD + m) * HD + n];
            cmb[m * 33 + n] = acc;
        }
        __syncthreads();
        for (int i = tid; i < HD * HD; i += 256) {
            int a = i >> 5, bq = i & 31;
            Ws[((cc * NH + h) * HD + a) * HD + bq] = cmb[a * 33 + bq];
            WT[((size_t)(cc * NH + h) * HD + a) * HD + bq] = f2b(cmb[bq * 33 + a]);
        }
        return;
    }
    if (g < 208) {  // transpose Wq/Wk/Wv
        int t = g - 160;
        int tw = t >> 2, ob = t & 3;
        int which = tw >> 2, ty = tw & 3;
        const float* src = ((which == 0) ? Wq : (which == 1) ? Wk : Wv) + (size_t)ty * EMB * EMB;
        int out0 = ob * 64;
        for (int it = 0; it < 16; it++) {
            int e = it * 16 + (tid >> 4);
            int o4 = (tid & 15) * 4;
            float4 v = *(const float4*)&src[(size_t)e * EMB + out0 + o4];
            ls[(o4 + 0) * 264 + e] = f2b(v.x);
            ls[(o4 + 1) * 264 + e] = f2b(v.y);
            ls[(o4 + 2) * 264 + e] = f2b(v.z);
            ls[(o4 + 3) * 264 + e] = f2b(v.w);
        }
        __syncthreads();
        int out = tid >> 2, ech = (tid & 3) * 8;
        unsigned short* dst = Wt + (size_t)tw * EMB * EMB + (size_t)(out0 + out) * EMB;
        const unsigned short* srcl = &ls[out * 264];
#pragma unroll
        for (int jj = 0; jj < 8; jj++)
            *(uint4*)&dst[ech + jj * 32] = *(const uint4*)&srcl[ech + jj * 32];
        return;
    }
    // mask check: 256 blocks x 4096 floats; write per-block flag (no init needed)
    {
        int idx = g - 208;
        const uint4* p = (const uint4*)am + (size_t)idx * 1024;
        unsigned o = 0;
#pragma unroll
        for (int j = 0; j < 4; j++) {
            uint4 v = p[tid + j * 256];
            o |= v.x | v.y | v.z | v.w;
        }
        int wv = __any(o != 0);
        if ((tid & 63) == 0) reds[tid >> 6] = wv;
        __syncthreads();
        if (tid == 0) mflagArr[idx] = reds[0] | reds[1] | reds[2] | reds[3];
    }
}

// ---------------- K1: QKV projection; V emitted transposed+padded (vpT[b][n256][640]) ----------------
__global__ __launch_bounds__(256, 4) void k_qkv(
    const float* __restrict__ x, const int* __restrict__ ts,
    const unsigned short* __restrict__ Wt,
    unsigned short* __restrict__ qp, unsigned short* __restrict__ kp,
    unsigned short* __restrict__ vpT) {
    __shared__ int spk[LL];
    __shared__ unsigned long long wtll[4];
    __shared__ int msc[16];
    __shared__ unsigned short vt_l[128 * 33];   // 8448 B transpose tile (V path only)

    int g = blockIdx.x, tid = threadIdx.x;
    int ns = g % 6, gb = g / 6;
    int b = gb >> 4, tb = gb & 15, i0 = tb * 32;
    int which = ns >> 1, nh = ns & 1;
    int wave = tid >> 6, lane = tid & 63, quad = lane >> 4, col = lane & 15;

    sort512(ts + b * LL, spk, wtll, msc, tid);

    // preload A-frags (x rows, sorted) straight into registers
    bf16x8 afr[2][8];
#pragma unroll
    for (int mt = 0; mt < 2; mt++) {
        int orig = spk[i0 + mt * 16 + col] & 0xFFFF;
        const float* xr = &x[(size_t)(b * LL + orig) * EMB];
#pragma unroll
        for (int kc = 0; kc < 8; kc++) {
            float4 v0 = *(const float4*)&xr[kc * 32 + quad * 8];
            float4 v1 = *(const float4*)&xr[kc * 32 + quad * 8 + 4];
            uint4 up;
            up.x = pack2(v0.x, v0.y); up.y = pack2(v0.z, v0.w);
            up.z = pack2(v1.x, v1.y); up.w = pack2(v1.z, v1.w);
            afr[mt][kc] = *(bf16x8*)&up;
        }
    }
    int t_start = spk[i0] >> 16, t_end = spk[i0 + 31] >> 16;
    unsigned short* outp = (which == 0) ? qp : kp;

    for (int ty = t_start; ty <= t_end; ty++) {
        f32x4 acc[2][2];
#pragma unroll
        for (int mt = 0; mt < 2; mt++)
#pragma unroll
            for (int nt = 0; nt < 2; nt++) acc[mt][nt] = (f32x4){0.f, 0.f, 0.f, 0.f};
        const unsigned short* wsrc = Wt + (size_t)(which * 4 + ty) * EMB * EMB + (size_t)(nh * 128) * EMB;
        const unsigned short* w0 = &wsrc[(size_t)((wave * 2 + 0) * 16 + col) * EMB + quad * 8];
        const unsigned short* w1 = &wsrc[(size_t)((wave * 2 + 1) * 16 + col) * EMB + quad * 8];
#pragma unroll
        for (int kc = 0; kc < 8; kc++) {
            bf16x8 b0 = *(const bf16x8*)&w0[kc * 32];
            bf16x8 b1 = *(const bf16x8*)&w1[kc * 32];
            acc[0][0] = __builtin_amdgcn_mfma_f32_16x16x32_bf16(afr[0][kc], b0, acc[0][0], 0, 0, 0);
            acc[0][1] = __builtin_amdgcn_mfma_f32_16x16x32_bf16(afr[0][kc], b1, acc[0][1], 0, 0, 0);
            acc[1][0] = __builtin_amdgcn_mfma_f32_16x16x32_bf16(afr[1][kc], b0, acc[1][0], 0, 0, 0);
            acc[1][1] = __builtin_amdgcn_mfma_f32_16x16x32_bf16(afr[1][kc], b1, acc[1][1], 0, 0, 0);
        }
        if (which < 2) {
#pragma unroll
            for (int mt = 0; mt < 2; mt++)
#pragma unroll
                for (int r = 0; r < 4; r++) {
                    int tokloc = mt * 16 + quad * 4 + r;
                    int tty = spk[i0 + tokloc] >> 16;
                    if (tty != ty) continue;
#pragma unroll
                    for (int nt = 0; nt < 2; nt++) {
                        int n = nh * 128 + (wave * 2 + nt) * 16 + col;
                        int h = n >> 5, d = n & 31;
                        outp[((size_t)(b * NH + h) * LL + i0 + tokloc) * HD + d] = f2b(acc[mt][nt][r]);
                    }
                }
        } else {
            // stage tile [ln 128][tok 32] then write this type's token range, coalesced
#pragma unroll
            for (int mt = 0; mt < 2; mt++)
#pragma unroll
                for (int nt = 0; nt < 2; nt++) {
                    int ln = (wave * 2 + nt) * 16 + col;
#pragma unroll
                    for (int r = 0; r < 4; r++)
                        vt_l[ln * 33 + mt * 16 + quad * 4 + r] = f2b(acc[mt][nt][r]);
                }
            __syncthreads();
            int ub = msc[4 + ty], cnt = msc[8 + ty], pb = msc[ty];
            int lo = ub - i0; if (lo < 0) lo = 0;
            int hi = ub + cnt - i0; if (hi > 32) hi = 32;
            int run = hi - lo;
            int pbase = pb + i0 + lo - ub;
            int rowbase = b * 256 + nh * 128;
            int t32 = tid & 31;
            if (t32 < run) {
                for (int rr = tid >> 5; rr < 128; rr += 8)
                    vpT[(size_t)(rowbase + rr) * 640 + pbase + t32] = vt_l[rr * 33 + lo + t32];
            }
            __syncthreads();
        }
    }
}

// ---------------- K2: attention core ----------------
#define SCP 648
#define OFF_UN   20736
#define OFF_QTB  29184
#define OFF_KPAD 33536
#define OFF_TBL  36096
#define OFF_RPL  37120
#define OFF_WT   38400
#define OFF_QOR  38432
#define OFF_QTY  38496
#define OFF_INV  38560
#define OFF_MSC  38624
#define SM_TOTAL 38688
__global__ __launch_bounds__(256, 4) void k_attn(
    const unsigned short* __restrict__ qp, const unsigned short* __restrict__ kp,
    const unsigned short* __restrict__ vpT,
    const int* __restrict__ ts, const float* __restrict__ rp, const float* __restrict__ am,
    const float* __restrict__ W1s, const float* __restrict__ W2s,
    const unsigned short* __restrict__ W1Tb, const unsigned short* __restrict__ W2Tb,
    const int* __restrict__ mflagArr, float* __restrict__ ctx) {
    __shared__ __align__(16) char smem[SM_TOTAL];
    __shared__ int msk_s;
    unsigned short* scu = (unsigned short*)smem;
    int*   spk  = (int*)smem;
    unsigned short* qstb = (unsigned short*)(smem + OFF_UN);   // [16*40]
    float* sb   = (float*)(smem + OFF_UN);                     // [16*132]
    unsigned short* qtb = (unsigned short*)(smem + OFF_QTB);   // [16*136] / later sbb
    unsigned short* sbb = (unsigned short*)(smem + OFF_QTB);
    int*   kpad = (int*)(smem + OFF_KPAD);                     // [640]: ty<<20 | upos<<10 | orig
    short* tbl  = (short*)(smem + OFF_TBL);
    float* rp_l = (float*)(smem + OFF_RPL);
    unsigned long long* wtll = (unsigned long long*)(smem + OFF_WT);
    int*   qor_l = (int*)(smem + OFF_QOR);
    int*   qty_l = (int*)(smem + OFF_QTY);
    float* inv_l = (float*)(smem + OFF_INV);
    int*   msc   = (int*)(smem + OFF_MSC);

    int blk = blockIdx.x;
    int b = blk >> 8, h = (blk >> 5) & 7, q16 = blk & 31;
    int i0q = q16 * 16;
    int tid = threadIdx.x;
    int wave = tid >> 6, lane = tid & 63, quad = lane >> 4, col = lane & 15;
    int bh = b * NH + h;

    if (wave == 0) {   // OR-reduce 256 mask flags (written unconditionally by k_pre)
        int v = 0;
#pragma unroll
        for (int j = 0; j < 4; j++) v |= mflagArr[lane + 64 * j];
        int anyv = __any(v != 0);
        if (lane == 0) msk_s = anyv;
    }
    for (int d = tid; d < LL; d += 256) {
        int v;
        if (d < 8) v = d;
        else {
            double r = log((double)d / 8.0) / log(5.0);
            v = 8 + (int)(r * 8.0);
            if (v > 15) v = 15;
        }
        tbl[d] = (short)v;
    }
    for (int i = tid; i < CCN * NBKT; i += 256) rp_l[i] = rp[i * NH + h];

    sort512(ts + b * LL, spk, wtll, msc, tid);   // barriers publish msk_s/tbl/rp_l too

    int KT = msc[12];
    int mz = (msk_s == 0);
    if (tid < 16) {
        int v = spk[i0q + tid];
        qor_l[tid] = v & 0xFFFF; qty_l[tid] = v >> 16;
    }
    for (int pos = tid; pos < KT; pos += 256) {
        int real, upos, seg;
        pad_lookup(msc, pos, real, upos, seg);
        int orig = real ? (spk[upos] & 0xFFFF) : 0x3FF;
        kpad[pos] = (seg << 20) | ((real ? upos : 0) << 10) | orig;
    }
    {   // stage 16 q rows (bf16, pitch 40)
        int q = tid >> 4, m2 = (tid & 15) * 2;
        ((unsigned*)qstb)[q * 20 + (tid & 15)] =
            *(const unsigned*)&qp[((size_t)bh * LL + i0q + q) * HD + m2];
    }
    __syncthreads();

    int qor_r[4], qty_r[4];
#pragma unroll
    for (int r = 0; r < 4; r++) { qor_r[r] = qor_l[quad * 4 + r]; qty_r[r] = qty_l[quad * 4 + r]; }
    bool uniq = (qty_l[0] == qty_l[15]);
    int tqu = qty_l[0];

    // ---- qt ----
    if (uniq) {
#pragma unroll
        for (int it = 0; it < 2; it++) {
            int t8 = wave * 2 + it;
            int tk = t8 >> 1, nhf = t8 & 1;
            int bmv = bm_of(tqu, tk);
            bf16x8 a = *(const bf16x8*)&qstb[col * 40 + quad * 8];
            bf16x8 bb = *(const bf16x8*)&W1Tb[((size_t)(bmv * NH + h) * HD + nhf * 16 + col) * HD + quad * 8];
            f32x4 d = {0.f, 0.f, 0.f, 0.f};
            d = __builtin_amdgcn_mfma_f32_16x16x32_bf16(a, bb, d, 0, 0, 0);
#pragma unroll
            for (int r = 0; r < 4; r++)
                qtb[(quad * 4 + r) * 136 + tk * 32 + nhf * 16 + col] = f2b(d[r]);
        }
    } else {
        for (int i = tid; i < 16 * 128; i += 256) {
            int q = i >> 7, r = i & 127, tk = r >> 5, n = r & 31;
            int bmv = bm_of(qty_l[q], tk);
            const float* wb = &W1s[((bmv * NH + h) * HD) * HD + n];
            float acc = 0.f;
#pragma unroll
            for (int m = 0; m < HD; m++) acc += b2f(qstb[q * 40 + m]) * wb[m * HD];
            qtb[q * 136 + tk * 32 + n] = f2b(acc);
        }
    }
    __syncthreads();

    // ---- pass 1: scores, barrier-free, direct K loads ----
    const float* amb = am + (size_t)b * LL * LL;
    int ntiles = KT >> 4;
    for (int tile = wave; tile < ntiles; tile += 4) {
        int kb = tile * 16;
        int kv0 = kpad[kb];
        if ((kv0 & 0x3FF) == 0x3FF) {
#pragma unroll
            for (int r = 0; r < 4; r++) scu[(quad * 4 + r) * SCP + kb + col] = 0xFF80;
            continue;
        }
        int tkt = kv0 >> 20;
        int kpi = kb + col;
        int kv = kpad[kpi];
        int ko = kv & 0x3FF;
        int upos = (kv >> 10) & 0x3FF;
        bool real = (ko != 0x3FF);
        bf16x8 bfr;
        if (real) bfr = *(const bf16x8*)&kp[((size_t)bh * LL + upos) * HD + quad * 8];
        else { uint4 z = make_uint4(0, 0, 0, 0); bfr = *(bf16x8*)&z; }
        bf16x8 a = *(const bf16x8*)&qtb[col * 136 + tkt * 32 + quad * 8];
        f32x4 d = {0.f, 0.f, 0.f, 0.f};
        d = __builtin_amdgcn_mfma_f32_16x16x32_bf16(a, bfr, d, 0, 0, 0);
        if (!real) {
#pragma unroll
            for (int r = 0; r < 4; r++) scu[(quad * 4 + r) * SCP + kpi] = 0xFF80;
        } else {
#pragma unroll
            for (int r = 0; r < 4; r++) {
                int q = quad * 4 + r;
                int qo = qor_r[r];
                int dd = qo - ko;
                int ad = dd < 0 ? -dd : dd;
                int bk = (dd < 0 ? 16 : 0) + (int)tbl[ad];
                float sv = d[r] * SCALE + rp_l[bm_of(qty_r[r], tkt) * NBKT + bk];
                if (!mz) sv += amb[(size_t)qo * LL + ko];
                scu[q * SCP + kpi] = f2b(sv);
            }
        }
    }
    __syncthreads();

    // ---- pass 2: softmax ----
    {
        int gq = tid >> 4, t16 = tid & 15;
        float mx = -1e30f;
        for (int kk = t16; kk < KT; kk += 16) mx = fmaxf(mx, b2f(scu[gq * SCP + kk]));
#pragma unroll
        for (int off = 1; off < 16; off <<= 1) mx = fmaxf(mx, __shfl_xor(mx, off, 16));
        float sum = 0.f;
        for (int kk = t16; kk < KT; kk += 16) {
            int idx = gq * SCP + kk;
            float e = __expf(b2f(scu[idx]) - mx);
            scu[idx] = f2b(e); sum += e;
        }
#pragma unroll
        for (int off = 1; off < 16; off <<= 1) sum += __shfl_xor(sum, off, 16);
        if (t16 == 0) inv_l[gq] = 1.0f / sum;
    }
    __syncthreads();

    // ---- pass 3: PV via MFMA, barrier-free, direct vpT B-frag loads ----
    f32x4 accv[4][2];
#pragma unroll
    for (int t = 0; t < 4; t++)
#pragma unroll
        for (int hh = 0; hh < 2; hh++) accv[t][hh] = (f32x4){0.f, 0.f, 0.f, 0.f};

    const unsigned short* vbase = &vpT[(size_t)(b * 256 + h * 32) * 640];
    int ngroups = KT >> 5;
    for (int gg = wave; gg < ngroups; gg += 4) {
        int loc = gg << 5;
        int kvg = kpad[loc];
        if ((kvg & 0x3FF) == 0x3FF) continue;   // all-pad group (pads only at segment tails)
        int tk = kvg >> 20;
        bf16x8 a = *(const bf16x8*)&scu[col * SCP + loc + quad * 8];
        bf16x8 b0 = *(const bf16x8*)&vbase[(size_t)col * 640 + loc + quad * 8];
        bf16x8 b1 = *(const bf16x8*)&vbase[(size_t)(col + 16) * 640 + loc + quad * 8];
        if (tk == 0) {
            accv[0][0] = __builtin_amdgcn_mfma_f32_16x16x32_bf16(a, b0, accv[0][0], 0, 0, 0);
            accv[0][1] = __builtin_amdgcn_mfma_f32_16x16x32_bf16(a, b1, accv[0][1], 0, 0, 0);
        } else if (tk == 1) {
            accv[1][0] = __builtin_amdgcn_mfma_f32_16x16x32_bf16(a, b0, accv[1][0], 0, 0, 0);
            accv[1][1] = __builtin_amdgcn_mfma_f32_16x16x32_bf16(a, b1, accv[1][1], 0, 0, 0);
        } else if (tk == 2) {
            accv[2][0] = __builtin_amdgcn_mfma_f32_16x16x32_bf16(a, b0, accv[2][0], 0, 0, 0);
            accv[2][1] = __builtin_amdgcn_mfma_f32_16x16x32_bf16(a, b1, accv[2][1], 0, 0, 0);
        } else {
            accv[3][0] = __builtin_amdgcn_mfma_f32_16x16x32_bf16(a, b0, accv[3][0], 0, 0, 0);
            accv[3][1] = __builtin_amdgcn_mfma_f32_16x16x32_bf16(a, b1, accv[3][1], 0, 0, 0);
        }
    }
    __syncthreads();

    // ---- cross-wave reduction; last wave emits bf16 sbb ----
#pragma unroll
    for (int w = 0; w < 4; w++) {
        if (wave == w) {
#pragma unroll
            for (int t = 0; t < 4; t++)
#pragma unroll
                for (int hh = 0; hh < 2; hh++)
#pragma unroll
                    for (int r = 0; r < 4; r++) {
                        int q = quad * 4 + r;
                        int n = col + 16 * hh;
                        float val = accv[t][hh][r];
                        if (w == 0) {
                            sb[q * 132 + t * 32 + n] = val;
                        } else if (w < 3) {
                            sb[q * 132 + t * 32 + n] += val;
                        } else {
                            float fin = sb[q * 132 + t * 32 + n] + val;
                            sb[q * 132 + t * 32 + n] = fin;
                            sbb[q * 136 + t * 32 + n] = f2b(fin);
                        }
                    }
        }
        __syncthreads();
    }

    // ---- ctx epilogue ----
    if (uniq) {
        if (wave < 2) {
            int mhf = wave;
            f32x4 d = {0.f, 0.f, 0.f, 0.f};
#pragma unroll
            for (int tk = 0; tk < 4; tk++) {
                int bmv = bm_of(tqu, tk);
                bf16x8 a = *(const bf16x8*)&sbb[col * 136 + tk * 32 + quad * 8];
                bf16x8 bb = *(const bf16x8*)&W2Tb[((size_t)(bmv * NH + h) * HD + mhf * 16 + col) * HD + quad * 8];
                d = __builtin_amdgcn_mfma_f32_16x16x32_bf16(a, bb, d, 0, 0, 0);
            }
#pragma unroll
            for (int r = 0; r < 4; r++) {
                int q = quad * 4 + r;
                ctx[((size_t)(b * LL + qor_l[q])) * EMB + h * HD + mhf * 16 + col] = d[r] * inv_l[q];
            }
        }
    } else {
        int m = tid & 31, qq = tid >> 5;
#pragma unroll
        for (int rep = 0; rep < 2; rep++) {
            int qi = qq + 8 * rep;
            int tq = qty_l[qi];
            float acc = 0.f;
#pragma unroll
            for (int tk2 = 0; tk2 < 4; tk2++) {
                int bmv = bm_of(tq, tk2);
                const float* wb = &W2s[((bmv * NH + h) * HD) * HD + m];
                const float* sbp = &sb[qi * 132 + tk2 * 32];
                for (int n = 0; n < HD; n++) acc += sbp[n] * wb[n * HD];
            }
            int qo = qor_l[qi];
            ctx[((size_t)(b * LL + qo)) * EMB + h * HD + m] = acc * inv_l[qi];
        }
    }
}

// ---------------- K3: residual + LayerNorm ----------------
__global__ void k_ln(const float* __restrict__ ctx, const float* __restrict__ x,
                     const float* __restrict__ gamma, const float* __restrict__ beta,
                     float* __restrict__ out) {
    __shared__ float red[8];
    __shared__ float red2[8];
    int blk = blockIdx.x;
    int b = blk >> 9, l = blk & 511;
    int j = threadIdx.x;
    size_t base = ((size_t)(b * LL + l)) * EMB;
    float v = ctx[base + j] + x[base + j];
    float s = v, s2 = v * v;
    for (int off = 32; off > 0; off >>= 1) { s += __shfl_down(s, off, 64); s2 += __shfl_down(s2, off, 64); }
    int wid = j >> 6;
    if ((j & 63) == 0) { red[wid] = s; red2[wid] = s2; }
    __syncthreads();
    if (j == 0) {
        float ts_ = 0, ts2 = 0;
        for (int w = 0; w < 4; w++) { ts_ += red[w]; ts2 += red2[w]; }
        red[4] = ts_; red2[4] = ts2;
    }
    __syncthreads();
    float mu = red[4] / (float)EMB;
    float var = red2[4] / (float)EMB - mu * mu;
    float r = rsqrtf(var + 1e-12f);
    out[base + j] = (v - mu) * r * gamma[j] + beta[j];
}

extern "C" void kernel_launch(void* const* d_in, const int* in_sizes, int n_in,
                              void* d_out, int out_size, void* d_ws, size_t ws_size,
                              hipStream_t stream) {
    const float* x  = (const float*)d_in[0];
    const float* am = (const float*)d_in[1];
    const int*   ts = (const int*)d_in[2];
    const float* Wq = (const float*)d_in[3];
    const float* Wk = (const float*)d_in[4];
    const float* Wv = (const float*)d_in[5];
    const float* W1 = (const float*)d_in[6];
    const float* a1 = (const float*)d_in[7];
    const float* W2 = (const float*)d_in[8];
    const float* a2 = (const float*)d_in[9];
    const float* rp = (const float*)d_in[10];
    const float* g  = (const float*)d_in[11];
    const float* be = (const float*)d_in[12];
    float* out = (float*)d_out;

    float* ws  = (float*)d_ws;
    float* W1s = ws;                                        // 81920 f
    float* W2s = ws + 81920;                                // 81920 f
    unsigned short* W1Tb = (unsigned short*)(ws + 163840);  // 40960 f
    unsigned short* W2Tb = (unsigned short*)(ws + 204800);  // 40960 f
    int* mflagArr = (int*)(ws + 245760);                    // 256 i
    unsigned short* qp = (unsigned short*)(ws + 246016);    // 262144 f (bf16 x 524288)
    unsigned short* kp = qp + BB * NH * LL * HD;            // 262144 f
    unsigned short* vpT = kp + BB * NH * LL * HD;           // 327680 f (bf16 x 655360, padded 640)
    float* ctx = (float*)(vpT + BB * 256 * 640);            // 524288 f
    unsigned short* Wt = (unsigned short*)ctx;              // aliases ctx (dead until k_attn)

    hipLaunchKernelGGL(k_pre, dim3(464), dim3(256), 0, stream,
                       a1, W1, a2, W2, Wq, Wk, Wv, am, W1s, W2s, W1Tb, W2Tb, Wt, mflagArr);
    hipLaunchKernelGGL(k_qkv, dim3(384), dim3(256), 0, stream, x, ts, Wt, qp, kp, vpT);
    hipLaunchKernelGGL(k_attn, dim3(BB * NH * 32), dim3(256), 0, stream,
                       qp, kp, vpT, ts, rp, am, W1s, W2s, W1Tb, W2Tb, mflagArr, ctx);
    hipLaunchKernelGGL(k_ln, dim3(BB * LL), dim3(256), 0, stream, ctx, x, g, be, out);
}

// Round 11
// 139.006 us; speedup vs baseline: 1.0405x; 1.0120x over previous
//
#include <hip/hip_runtime.h>
#include <math.h>

#define BB 4
#define LL 512
#define EMB 256
#define NH 8
#define HD 32
#define NB_ 3
#define CCN 10
#define NBKT 32
#define SCALE 0.17677669529663687f

typedef __bf16 bf16_t;
typedef __attribute__((ext_vector_type(8))) bf16_t bf16x8;
typedef __attribute__((ext_vector_type(4))) float f32x4;

__device__ __forceinline__ unsigned short f2b(float f) {
    unsigned int u = __float_as_uint(f);
    u += 0x7FFF + ((u >> 16) & 1);   // RNE
    return (unsigned short)(u >> 16);
}
__device__ __forceinline__ float b2f(unsigned short s) {
    return __uint_as_float(((unsigned int)s) << 16);
}
__device__ __forceinline__ unsigned pack2(float a, float b) {
    return (unsigned)f2b(a) | ((unsigned)f2b(b) << 16);
}
__device__ __forceinline__ int bm_of(int tq, int tk) {
    return (tq * tk != 0) ? ((tq - 1) * 3 + tk) : 0;
}
__device__ __forceinline__ unsigned long long shfl_up64(unsigned long long v, int d) {
    unsigned lo = (unsigned)__shfl_up((int)(unsigned)v, d, 64);
    unsigned hi = (unsigned)__shfl_up((int)(v >> 32), d, 64);
    return (((unsigned long long)hi) << 32) | lo;
}

// Stable counting sort of 512 tokens by type (4 types), 256 threads.
__device__ __forceinline__ void sort512(const int* __restrict__ tsb, int* spk,
                                        unsigned long long* wtll, int* msc, int tid) {
    int ty0 = tsb[2 * tid], ty1 = tsb[2 * tid + 1];
    unsigned long long pk = (1ULL << (16 * ty0)) + (1ULL << (16 * ty1));
    unsigned long long v = pk;
    int lane = tid & 63;
#pragma unroll
    for (int off = 1; off < 64; off <<= 1) {
        unsigned long long o = shfl_up64(v, off);
        if (lane >= off) v += o;
    }
    int w = tid >> 6;
    if (lane == 63) wtll[w] = v;
    __syncthreads();
    unsigned long long pre = 0, tot = 0;
#pragma unroll
    for (int i = 0; i < 4; i++) {
        unsigned long long xx = wtll[i];
        if (i < w) pre += xx;
        tot += xx;
    }
    v += pre;
    unsigned long long excl = v - pk;
    int c0 = (int)(tot & 0xFFFF), c1 = (int)((tot >> 16) & 0xFFFF);
    int c2 = (int)((tot >> 32) & 0xFFFF), c3 = (int)((tot >> 48) & 0xFFFF);
    int ub0 = 0, ub1 = c0, ub2 = c0 + c1, ub3 = c0 + c1 + c2;
    if (tid == 0) {
        int pc0 = (c0 + 31) & ~31, pc1 = (c1 + 31) & ~31, pc2 = (c2 + 31) & ~31, pc3 = (c3 + 31) & ~31;
        int pb1 = pc0, pb2 = pc0 + pc1, pb3 = pc0 + pc1 + pc2;
        msc[0] = 0;  msc[1] = pb1; msc[2] = pb2; msc[3] = pb3;
        msc[4] = ub0; msc[5] = ub1; msc[6] = ub2; msc[7] = ub3;
        msc[8] = c0; msc[9] = c1; msc[10] = c2; msc[11] = c3;
        msc[12] = (pb3 + pc3 + 63) & ~63;
    }
    int bases[4] = {ub0, ub1, ub2, ub3};
    int r0 = (int)((excl >> (16 * ty0)) & 0xFFFF);
    unsigned long long excl1 = excl + (1ULL << (16 * ty0));
    int r1 = (int)((excl1 >> (16 * ty1)) & 0xFFFF);
    spk[bases[ty0] + r0] = (ty0 << 16) | (2 * tid);
    spk[bases[ty1] + r1] = (ty1 << 16) | (2 * tid + 1);
    __syncthreads();
}

__device__ __forceinline__ void pad_lookup(const int* msc, int pos, int& real, int& upos, int& seg) {
    seg = (pos >= msc[1]) + (pos >= msc[2]) + (pos >= msc[3]);
    int r = pos - msc[seg];
    real = (r < msc[8 + seg]) ? 1 : 0;
    upos = msc[4 + seg] + r;
}

// ---------------- K0: weight combine + W transpose + mask flags + SORT/KPAD/TBL precompute ----------------
// g<160: combine; 160<=g<208: Wq/k/v transpose; 208<=g<464: mask check;
// 464<=g<468: per-batch sort -> spkg/mscg/kpadg; g==468: bucket table -> tblg.
__global__ void k_pre(const float* __restrict__ A1, const float* __restrict__ W1,
                      const float* __restrict__ A2, const float* __restrict__ W2,
                      const float* __restrict__ Wq, const float* __restrict__ Wk, const float* __restrict__ Wv,
                      const float* __restrict__ am, const int* __restrict__ ts,
                      float* __restrict__ W1s, float* __restrict__ W2s,
                      unsigned short* __restrict__ W1Tb, unsigned short* __restrict__ W2Tb,
                      unsigned short* __restrict__ Wt, int* __restrict__ mflagArr,
                      int* __restrict__ spkg, int* __restrict__ mscg, int* __restrict__ kpadg,
                      short* __restrict__ tblg) {
    __shared__ float cmb[32 * 33];
    __shared__ unsigned short ls[64 * 264];
    __shared__ int reds[4];
    __shared__ int spk_s[LL];
    __shared__ unsigned long long wtll[4];
    __shared__ int msc_s[16];
    int g = blockIdx.x, tid = threadIdx.x;
    if (g < 160) {
        int idx = g;
        const float* alpha = (idx < 80) ? A1 : A2;
        const float* W     = (idx < 80) ? W1 : W2;
        float* Ws          = (idx < 80) ? W1s : W2s;
        unsigned short* WT = (idx < 80) ? W1Tb : W2Tb;
        idx %= 80;
        int cc = idx / NH, h = idx % NH;
        float a0 = alpha[cc * NB_ * NH + 0 * NH + h];
        float a1 = alpha[cc * NB_ * NH + 1 * NH + h];
        float a2 = alpha[cc * NB_ * NH + 2 * NH + h];
        float mx = fmaxf(a0, fmaxf(a1, a2));
        float e0 = __expf(a0 - mx), e1 = __expf(a1 - mx), e2 = __expf(a2 - mx);
        float inv = 1.0f / (e0 + e1 + e2);
        e0 *= inv; e1 *= inv; e2 *= inv;
        for (int i = tid; i < HD * HD; i += 256) {
            int m = i >> 5, n = i & 31;
            float acc = e0 * W[((0 * NH + h) * HD + m) * HD + n]
                      + e1 * W[((1 * NH + h) * HD + m) * HD + n]
                      + e2 * W[((2 * NH + h) * HD + m) * HD + n];
            cmb[m * 33 + n] = acc;
        }
        __syncthreads();
        for (int i = tid; i < HD * HD; i += 256) {
            int a = i >> 5, bq = i & 31;
            Ws[((cc * NH + h) * HD + a) * HD + bq] = cmb[a * 33 + bq];
            WT[((size_t)(cc * NH + h) * HD + a) * HD + bq] = f2b(cmb[bq * 33 + a]);
        }
        return;
    }
    if (g < 208) {  // transpose Wq/Wk/Wv
        int t = g - 160;
        int tw = t >> 2, ob = t & 3;
        int which = tw >> 2, ty = tw & 3;
        const float* src = ((which == 0) ? Wq : (which == 1) ? Wk : Wv) + (size_t)ty * EMB * EMB;
        int out0 = ob * 64;
        for (int it = 0; it < 16; it++) {
            int e = it * 16 + (tid >> 4);
            int o4 = (tid & 15) * 4;
            float4 v = *(const float4*)&src[(size_t)e * EMB + out0 + o4];
            ls[(o4 + 0) * 264 + e] = f2b(v.x);
            ls[(o4 + 1) * 264 + e] = f2b(v.y);
            ls[(o4 + 2) * 264 + e] = f2b(v.z);
            ls[(o4 + 3) * 264 + e] = f2b(v.w);
        }
        __syncthreads();
        int out = tid >> 2, ech = (tid & 3) * 8;
        unsigned short* dst = Wt + (size_t)tw * EMB * EMB + (size_t)(out0 + out) * EMB;
        const unsigned short* srcl = &ls[out * 264];
#pragma unroll
        for (int jj = 0; jj < 8; jj++)
            *(uint4*)&dst[ech + jj * 32] = *(const uint4*)&srcl[ech + jj * 32];
        return;
    }
    if (g < 464) {  // mask check
        int idx = g - 208;
        const uint4* p = (const uint4*)am + (size_t)idx * 1024;
        unsigned o = 0;
#pragma unroll
        for (int j = 0; j < 4; j++) {
            uint4 v = p[tid + j * 256];
            o |= v.x | v.y | v.z | v.w;
        }
        int wv = __any(o != 0);
        if ((tid & 63) == 0) reds[tid >> 6] = wv;
        __syncthreads();
        if (tid == 0) mflagArr[idx] = reds[0] | reds[1] | reds[2] | reds[3];
        return;
    }
    if (g < 468) {  // per-batch sort + kpad precompute
        int b = g - 464;
        sort512(ts + b * LL, spk_s, wtll, msc_s, tid);
        for (int i = tid; i < LL; i += 256) spkg[b * LL + i] = spk_s[i];
        if (tid < 16) mscg[b * 16 + tid] = msc_s[tid];
        int KT = msc_s[12];
        for (int pos = tid; pos < KT; pos += 256) {
            int real, upos, seg;
            pad_lookup(msc_s, pos, real, upos, seg);
            int orig = real ? (spk_s[upos] & 0xFFFF) : 0x3FF;
            kpadg[b * 640 + pos] = (seg << 20) | ((real ? upos : 0) << 10) | orig;
        }
        return;
    }
    // bucket table
    for (int d = tid; d < LL; d += 256) {
        int v;
        if (d < 8) v = d;
        else {
            double r = log((double)d / 8.0) / log(5.0);
            v = 8 + (int)(r * 8.0);
            if (v > 15) v = 15;
        }
        tblg[d] = (short)v;
    }
}

// ---------------- K1: QKV projection; V emitted transposed+padded ----------------
__global__ __launch_bounds__(256, 4) void k_qkv(
    const float* __restrict__ x, const int* __restrict__ spkg, const int* __restrict__ mscg,
    const unsigned short* __restrict__ Wt,
    unsigned short* __restrict__ qp, unsigned short* __restrict__ kp,
    unsigned short* __restrict__ vpT) {
    __shared__ int spk[LL];
    __shared__ int msc[16];
    __shared__ unsigned short vt_l[128 * 33];

    int g = blockIdx.x, tid = threadIdx.x;
    int ns = g % 6, gb = g / 6;
    int b = gb >> 4, tb = gb & 15, i0 = tb * 32;
    int which = ns >> 1, nh = ns & 1;
    int wave = tid >> 6, lane = tid & 63, quad = lane >> 4, col = lane & 15;

    spk[tid] = spkg[b * LL + tid];
    spk[tid + 256] = spkg[b * LL + tid + 256];
    if (tid < 16) msc[tid] = mscg[b * 16 + tid];
    __syncthreads();

    bf16x8 afr[2][8];
#pragma unroll
    for (int mt = 0; mt < 2; mt++) {
        int orig = spk[i0 + mt * 16 + col] & 0xFFFF;
        const float* xr = &x[(size_t)(b * LL + orig) * EMB];
#pragma unroll
        for (int kc = 0; kc < 8; kc++) {
            float4 v0 = *(const float4*)&xr[kc * 32 + quad * 8];
            float4 v1 = *(const float4*)&xr[kc * 32 + quad * 8 + 4];
            uint4 up;
            up.x = pack2(v0.x, v0.y); up.y = pack2(v0.z, v0.w);
            up.z = pack2(v1.x, v1.y); up.w = pack2(v1.z, v1.w);
            afr[mt][kc] = *(bf16x8*)&up;
        }
    }
    int t_start = spk[i0] >> 16, t_end = spk[i0 + 31] >> 16;
    unsigned short* outp = (which == 0) ? qp : kp;

    for (int ty = t_start; ty <= t_end; ty++) {
        f32x4 acc[2][2];
#pragma unroll
        for (int mt = 0; mt < 2; mt++)
#pragma unroll
            for (int nt = 0; nt < 2; nt++) acc[mt][nt] = (f32x4){0.f, 0.f, 0.f, 0.f};
        const unsigned short* wsrc = Wt + (size_t)(which * 4 + ty) * EMB * EMB + (size_t)(nh * 128) * EMB;
        const unsigned short* w0 = &wsrc[(size_t)((wave * 2 + 0) * 16 + col) * EMB + quad * 8];
        const unsigned short* w1 = &wsrc[(size_t)((wave * 2 + 1) * 16 + col) * EMB + quad * 8];
#pragma unroll
        for (int kc = 0; kc < 8; kc++) {
            bf16x8 b0 = *(const bf16x8*)&w0[kc * 32];
            bf16x8 b1 = *(const bf16x8*)&w1[kc * 32];
            acc[0][0] = __builtin_amdgcn_mfma_f32_16x16x32_bf16(afr[0][kc], b0, acc[0][0], 0, 0, 0);
            acc[0][1] = __builtin_amdgcn_mfma_f32_16x16x32_bf16(afr[0][kc], b1, acc[0][1], 0, 0, 0);
            acc[1][0] = __builtin_amdgcn_mfma_f32_16x16x32_bf16(afr[1][kc], b0, acc[1][0], 0, 0, 0);
            acc[1][1] = __builtin_amdgcn_mfma_f32_16x16x32_bf16(afr[1][kc], b1, acc[1][1], 0, 0, 0);
        }
        if (which < 2) {
#pragma unroll
            for (int mt = 0; mt < 2; mt++)
#pragma unroll
                for (int r = 0; r < 4; r++) {
                    int tokloc = mt * 16 + quad * 4 + r;
                    int tty = spk[i0 + tokloc] >> 16;
                    if (tty != ty) continue;
#pragma unroll
                    for (int nt = 0; nt < 2; nt++) {
                        int n = nh * 128 + (wave * 2 + nt) * 16 + col;
                        int h = n >> 5, d = n & 31;
                        outp[((size_t)(b * NH + h) * LL + i0 + tokloc) * HD + d] = f2b(acc[mt][nt][r]);
                    }
                }
        } else {
#pragma unroll
            for (int mt = 0; mt < 2; mt++)
#pragma unroll
                for (int nt = 0; nt < 2; nt++) {
                    int ln = (wave * 2 + nt) * 16 + col;
#pragma unroll
                    for (int r = 0; r < 4; r++)
                        vt_l[ln * 33 + mt * 16 + quad * 4 + r] = f2b(acc[mt][nt][r]);
                }
            __syncthreads();
            int ub = msc[4 + ty], cnt = msc[8 + ty], pb = msc[ty];
            int lo = ub - i0; if (lo < 0) lo = 0;
            int hi = ub + cnt - i0; if (hi > 32) hi = 32;
            int run = hi - lo;
            int pbase = pb + i0 + lo - ub;
            int rowbase = b * 256 + nh * 128;
            int t32 = tid & 31;
            if (t32 < run) {
                for (int rr = tid >> 5; rr < 128; rr += 8)
                    vpT[(size_t)(rowbase + rr) * 640 + pbase + t32] = vt_l[rr * 33 + lo + t32];
            }
            __syncthreads();
        }
    }
}

// ---------------- K2: attention core (sort/kpad/tbl loaded from global) ----------------
#define SCP 648
#define OFF_UN   20736
#define OFF_QTB  29184
#define OFF_KPAD 33536
#define OFF_TBL  36096
#define OFF_RPL  37120
#define OFF_QOR  38400
#define OFF_QTY  38464
#define OFF_INV  38528
#define SM_TOTAL 38592
__global__ __launch_bounds__(256, 4) void k_attn(
    const unsigned short* __restrict__ qp, const unsigned short* __restrict__ kp,
    const unsigned short* __restrict__ vpT,
    const int* __restrict__ spkg, const int* __restrict__ mscg, const int* __restrict__ kpadg,
    const short* __restrict__ tblg,
    const float* __restrict__ rp, const float* __restrict__ am,
    const float* __restrict__ W1s, const float* __restrict__ W2s,
    const unsigned short* __restrict__ W1Tb, const unsigned short* __restrict__ W2Tb,
    const int* __restrict__ mflagArr, float* __restrict__ ctx) {
    __shared__ __align__(16) char smem[SM_TOTAL];
    __shared__ int msk_s;
    unsigned short* scu = (unsigned short*)smem;
    unsigned short* qstb = (unsigned short*)(smem + OFF_UN);   // [16*40]
    float* sb   = (float*)(smem + OFF_UN);                     // [16*132]
    unsigned short* qtb = (unsigned short*)(smem + OFF_QTB);   // [16*136] / later sbb
    unsigned short* sbb = (unsigned short*)(smem + OFF_QTB);
    int*   kpad = (int*)(smem + OFF_KPAD);                     // [640]
    short* tbl  = (short*)(smem + OFF_TBL);
    float* rp_l = (float*)(smem + OFF_RPL);
    int*   qor_l = (int*)(smem + OFF_QOR);
    int*   qty_l = (int*)(smem + OFF_QTY);
    float* inv_l = (float*)(smem + OFF_INV);

    int blk = blockIdx.x;
    int b = blk >> 8, h = (blk >> 5) & 7, q16 = blk & 31;
    int i0q = q16 * 16;
    int tid = threadIdx.x;
    int wave = tid >> 6, lane = tid & 63, quad = lane >> 4, col = lane & 15;
    int bh = b * NH + h;

    int KT = mscg[b * 16 + 12];
    if (wave == 0) {
        int v = 0;
#pragma unroll
        for (int j = 0; j < 4; j++) v |= mflagArr[lane + 64 * j];
        int anyv = __any(v != 0);
        if (lane == 0) msk_s = anyv;
    }
    if (tid < 16) {
        int v = spkg[b * LL + i0q + tid];
        qor_l[tid] = v & 0xFFFF; qty_l[tid] = v >> 16;
    }
    for (int pos = tid; pos < KT; pos += 256) kpad[pos] = kpadg[b * 640 + pos];
    ((int*)tbl)[tid] = ((const int*)tblg)[tid];   // 512 shorts = 256 ints
    for (int i = tid; i < CCN * NBKT; i += 256) rp_l[i] = rp[i * NH + h];
    {   // stage 16 q rows (bf16, pitch 40)
        int q = tid >> 4, m2 = (tid & 15) * 2;
        ((unsigned*)qstb)[q * 20 + (tid & 15)] =
            *(const unsigned*)&qp[((size_t)bh * LL + i0q + q) * HD + m2];
    }
    __syncthreads();

    int qor_r[4], qty_r[4];
#pragma unroll
    for (int r = 0; r < 4; r++) { qor_r[r] = qor_l[quad * 4 + r]; qty_r[r] = qty_l[quad * 4 + r]; }
    bool uniq = (qty_l[0] == qty_l[15]);
    int tqu = qty_l[0];
    int mz = (msk_s == 0);

    // ---- qt ----
    if (uniq) {
#pragma unroll
        for (int it = 0; it < 2; it++) {
            int t8 = wave * 2 + it;
            int tk = t8 >> 1, nhf = t8 & 1;
            int bmv = bm_of(tqu, tk);
            bf16x8 a = *(const bf16x8*)&qstb[col * 40 + quad * 8];
            bf16x8 bb = *(const bf16x8*)&W1Tb[((size_t)(bmv * NH + h) * HD + nhf * 16 + col) * HD + quad * 8];
            f32x4 d = {0.f, 0.f, 0.f, 0.f};
            d = __builtin_amdgcn_mfma_f32_16x16x32_bf16(a, bb, d, 0, 0, 0);
#pragma unroll
            for (int r = 0; r < 4; r++)
                qtb[(quad * 4 + r) * 136 + tk * 32 + nhf * 16 + col] = f2b(d[r]);
        }
    } else {
        for (int i = tid; i < 16 * 128; i += 256) {
            int q = i >> 7, r = i & 127, tk = r >> 5, n = r & 31;
            int bmv = bm_of(qty_l[q], tk);
            const float* wb = &W1s[((bmv * NH + h) * HD) * HD + n];
            float acc = 0.f;
#pragma unroll
            for (int m = 0; m < HD; m++) acc += b2f(qstb[q * 40 + m]) * wb[m * HD];
            qtb[q * 136 + tk * 32 + n] = f2b(acc);
        }
    }
    __syncthreads();

    // ---- pass 1: scores, barrier-free, direct K loads ----
    const float* amb = am + (size_t)b * LL * LL;
    int ntiles = KT >> 4;
    for (int tile = wave; tile < ntiles; tile += 4) {
        int kb = tile * 16;
        int kv0 = kpad[kb];
        if ((kv0 & 0x3FF) == 0x3FF) {
#pragma unroll
            for (int r = 0; r < 4; r++) scu[(quad * 4 + r) * SCP + kb + col] = 0xFF80;
            continue;
        }
        int tkt = kv0 >> 20;
        int kpi = kb + col;
        int kv = kpad[kpi];
        int ko = kv & 0x3FF;
        int upos = (kv >> 10) & 0x3FF;
        bool real = (ko != 0x3FF);
        bf16x8 bfr;
        if (real) bfr = *(const bf16x8*)&kp[((size_t)bh * LL + upos) * HD + quad * 8];
        else { uint4 z = make_uint4(0, 0, 0, 0); bfr = *(bf16x8*)&z; }
        bf16x8 a = *(const bf16x8*)&qtb[col * 136 + tkt * 32 + quad * 8];
        f32x4 d = {0.f, 0.f, 0.f, 0.f};
        d = __builtin_amdgcn_mfma_f32_16x16x32_bf16(a, bfr, d, 0, 0, 0);
        if (!real) {
#pragma unroll
            for (int r = 0; r < 4; r++) scu[(quad * 4 + r) * SCP + kpi] = 0xFF80;
        } else {
#pragma unroll
            for (int r = 0; r < 4; r++) {
                int q = quad * 4 + r;
                int qo = qor_r[r];
                int dd = qo - ko;
                int ad = dd < 0 ? -dd : dd;
                int bk = (dd < 0 ? 16 : 0) + (int)tbl[ad];
                float sv = d[r] * SCALE + rp_l[bm_of(qty_r[r], tkt) * NBKT + bk];
                if (!mz) sv += amb[(size_t)qo * LL + ko];
                scu[q * SCP + kpi] = f2b(sv);
            }
        }
    }
    __syncthreads();

    // ---- pass 2: softmax ----
    {
        int gq = tid >> 4, t16 = tid & 15;
        float mx = -1e30f;
        for (int kk = t16; kk < KT; kk += 16) mx = fmaxf(mx, b2f(scu[gq * SCP + kk]));
#pragma unroll
        for (int off = 1; off < 16; off <<= 1) mx = fmaxf(mx, __shfl_xor(mx, off, 16));
        float sum = 0.f;
        for (int kk = t16; kk < KT; kk += 16) {
            int idx = gq * SCP + kk;
            float e = __expf(b2f(scu[idx]) - mx);
            scu[idx] = f2b(e); sum += e;
        }
#pragma unroll
        for (int off = 1; off < 16; off <<= 1) sum += __shfl_xor(sum, off, 16);
        if (t16 == 0) inv_l[gq] = 1.0f / sum;
    }
    __syncthreads();

    // ---- pass 3: PV via MFMA, barrier-free, direct vpT B-frag loads ----
    f32x4 accv[4][2];
#pragma unroll
    for (int t = 0; t < 4; t++)
#pragma unroll
        for (int hh = 0; hh < 2; hh++) accv[t][hh] = (f32x4){0.f, 0.f, 0.f, 0.f};

    const unsigned short* vbase = &vpT[(size_t)(b * 256 + h * 32) * 640];
    int ngroups = KT >> 5;
    for (int gg = wave; gg < ngroups; gg += 4) {
        int loc = gg << 5;
        int kvg = kpad[loc];
        if ((kvg & 0x3FF) == 0x3FF) continue;
        int tk = kvg >> 20;
        bf16x8 a = *(const bf16x8*)&scu[col * SCP + loc + quad * 8];
        bf16x8 b0 = *(const bf16x8*)&vbase[(size_t)col * 640 + loc + quad * 8];
        bf16x8 b1 = *(const bf16x8*)&vbase[(size_t)(col + 16) * 640 + loc + quad * 8];
        if (tk == 0) {
            accv[0][0] = __builtin_amdgcn_mfma_f32_16x16x32_bf16(a, b0, accv[0][0], 0, 0, 0);
            accv[0][1] = __builtin_amdgcn_mfma_f32_16x16x32_bf16(a, b1, accv[0][1], 0, 0, 0);
        } else if (tk == 1) {
            accv[1][0] = __builtin_amdgcn_mfma_f32_16x16x32_bf16(a, b0, accv[1][0], 0, 0, 0);
            accv[1][1] = __builtin_amdgcn_mfma_f32_16x16x32_bf16(a, b1, accv[1][1], 0, 0, 0);
        } else if (tk == 2) {
            accv[2][0] = __builtin_amdgcn_mfma_f32_16x16x32_bf16(a, b0, accv[2][0], 0, 0, 0);
            accv[2][1] = __builtin_amdgcn_mfma_f32_16x16x32_bf16(a, b1, accv[2][1], 0, 0, 0);
        } else {
            accv[3][0] = __builtin_amdgcn_mfma_f32_16x16x32_bf16(a, b0, accv[3][0], 0, 0, 0);
            accv[3][1] = __builtin_amdgcn_mfma_f32_16x16x32_bf16(a, b1, accv[3][1], 0, 0, 0);
        }
    }
    __syncthreads();

    // ---- cross-wave reduction; last wave emits bf16 sbb ----
#pragma unroll
    for (int w = 0; w < 4; w++) {
        if (wave == w) {
#pragma unroll
            for (int t = 0; t < 4; t++)
#pragma unroll
                for (int hh = 0; hh < 2; hh++)
#pragma unroll
                    for (int r = 0; r < 4; r++) {
                        int q = quad * 4 + r;
                        int n = col + 16 * hh;
                        float val = accv[t][hh][r];
                        if (w == 0) {
                            sb[q * 132 + t * 32 + n] = val;
                        } else if (w < 3) {
                            sb[q * 132 + t * 32 + n] += val;
                        } else {
                            float fin = sb[q * 132 + t * 32 + n] + val;
                            sb[q * 132 + t * 32 + n] = fin;
                            sbb[q * 136 + t * 32 + n] = f2b(fin);
                        }
                    }
        }
        __syncthreads();
    }

    // ---- ctx epilogue ----
    if (uniq) {
        if (wave < 2) {
            int mhf = wave;
            f32x4 d = {0.f, 0.f, 0.f, 0.f};
#pragma unroll
            for (int tk = 0; tk < 4; tk++) {
                int bmv = bm_of(tqu, tk);
                bf16x8 a = *(const bf16x8*)&sbb[col * 136 + tk * 32 + quad * 8];
                bf16x8 bb = *(const bf16x8*)&W2Tb[((size_t)(bmv * NH + h) * HD + mhf * 16 + col) * HD + quad * 8];
                d = __builtin_amdgcn_mfma_f32_16x16x32_bf16(a, bb, d, 0, 0, 0);
            }
#pragma unroll
            for (int r = 0; r < 4; r++) {
                int q = quad * 4 + r;
                ctx[((size_t)(b * LL + qor_l[q])) * EMB + h * HD + mhf * 16 + col] = d[r] * inv_l[q];
            }
        }
    } else {
        int m = tid & 31, qq = tid >> 5;
#pragma unroll
        for (int rep = 0; rep < 2; rep++) {
            int qi = qq + 8 * rep;
            int tq = qty_l[qi];
            float acc = 0.f;
#pragma unroll
            for (int tk2 = 0; tk2 < 4; tk2++) {
                int bmv = bm_of(tq, tk2);
                const float* wb = &W2s[((bmv * NH + h) * HD) * HD + m];
                const float* sbp = &sb[qi * 132 + tk2 * 32];
                for (int n = 0; n < HD; n++) acc += sbp[n] * wb[n * HD];
            }
            int qo = qor_l[qi];
            ctx[((size_t)(b * LL + qo)) * EMB + h * HD + m] = acc * inv_l[qi];
        }
    }
}

// ---------------- K3: residual + LayerNorm ----------------
__global__ void k_ln(const float* __restrict__ ctx, const float* __restrict__ x,
                     const float* __restrict__ gamma, const float* __restrict__ beta,
                     float* __restrict__ out) {
    __shared__ float red[8];
    __shared__ float red2[8];
    int blk = blockIdx.x;
    int b = blk >> 9, l = blk & 511;
    int j = threadIdx.x;
    size_t base = ((size_t)(b * LL + l)) * EMB;
    float v = ctx[base + j] + x[base + j];
    float s = v, s2 = v * v;
    for (int off = 32; off > 0; off >>= 1) { s += __shfl_down(s, off, 64); s2 += __shfl_down(s2, off, 64); }
    int wid = j >> 6;
    if ((j & 63) == 0) { red[wid] = s; red2[wid] = s2; }
    __syncthreads();
    if (j == 0) {
        float ts_ = 0, ts2 = 0;
        for (int w = 0; w < 4; w++) { ts_ += red[w]; ts2 += red2[w]; }
        red[4] = ts_; red2[4] = ts2;
    }
    __syncthreads();
    float mu = red[4] / (float)EMB;
    float var = red2[4] / (float)EMB - mu * mu;
    float r = rsqrtf(var + 1e-12f);
    out[base + j] = (v - mu) * r * gamma[j] + beta[j];
}

extern "C" void kernel_launch(void* const* d_in, const int* in_sizes, int n_in,
                              void* d_out, int out_size, void* d_ws, size_t ws_size,
                              hipStream_t stream) {
    const float* x  = (const float*)d_in[0];
    const float* am = (const float*)d_in[1];
    const int*   ts = (const int*)d_in[2];
    const float* Wq = (const float*)d_in[3];
    const float* Wk = (const float*)d_in[4];
    const float* Wv = (const float*)d_in[5];
    const float* W1 = (const float*)d_in[6];
    const float* a1 = (const float*)d_in[7];
    const float* W2 = (const float*)d_in[8];
    const float* a2 = (const float*)d_in[9];
    const float* rp = (const float*)d_in[10];
    const float* g  = (const float*)d_in[11];
    const float* be = (const float*)d_in[12];
    float* out = (float*)d_out;

    float* ws  = (float*)d_ws;
    float* W1s = ws;                                        // 81920 f
    float* W2s = ws + 81920;                                // -> 163840
    unsigned short* W1Tb = (unsigned short*)(ws + 163840);  // 40960 f
    unsigned short* W2Tb = (unsigned short*)(ws + 204800);  // 40960 f -> 245760
    int* mflagArr = (int*)(ws + 245760);                    // 256 i -> 246016
    int* spkg = (int*)(ws + 246016);                        // 2048 i -> 248064
    int* mscg = (int*)(ws + 248064);                        // 64 i -> 248128
    int* kpadg = (int*)(ws + 248128);                       // 2560 i -> 250688
    short* tblg = (short*)(ws + 250688);                    // 512 s -> 250944
    unsigned short* qp = (unsigned short*)(ws + 250944);    // 262144 f
    unsigned short* kp = qp + BB * NH * LL * HD;            // 262144 f
    unsigned short* vpT = kp + BB * NH * LL * HD;           // 327680 f
    float* ctx = (float*)(vpT + BB * 256 * 640);            // 524288 f
    unsigned short* Wt = (unsigned short*)ctx;              // aliases ctx (dead until k_attn)

    hipLaunchKernelGGL(k_pre, dim3(469), dim3(256), 0, stream,
                       a1, W1, a2, W2, Wq, Wk, Wv, am, ts, W1s, W2s, W1Tb, W2Tb, Wt,
                       mflagArr, spkg, mscg, kpadg, tblg);
    hipLaunchKernelGGL(k_qkv, dim3(384), dim3(256), 0, stream, x, spkg, mscg, Wt, qp, kp, vpT);
    hipLaunchKernelGGL(k_attn, dim3(BB * NH * 32), dim3(256), 0, stream,
                       qp, kp, vpT, spkg, mscg, kpadg, tblg, rp, am, W1s, W2s, W1Tb, W2Tb, mflagArr, ctx);
    hipLaunchKernelGGL(k_ln, dim3(BB * LL), dim3(256), 0, stream, ctx, x, g, be, out);
}